// Round 1
// baseline (474.977 us; speedup 1.0000x reference)
//
#include <hip/hip_runtime.h>
#include <hip/hip_bf16.h>

typedef __bf16 bf16x8 __attribute__((ext_vector_type(8)));
typedef __bf16 bf16x4 __attribute__((ext_vector_type(4)));
typedef float f32x4 __attribute__((ext_vector_type(4)));

#define NEG_INF (-__builtin_inff())

// ---------------------------------------------------------------------------
// f32 -> bf16 conversion (vectorized, grid-stride)
// ---------------------------------------------------------------------------
__global__ void cvt_f32_bf16(const float* __restrict__ src, __bf16* __restrict__ dst, int n) {
    int idx = blockIdx.x * blockDim.x + threadIdx.x;
    int stride = gridDim.x * blockDim.x;
    for (int i = idx * 4; i < n; i += stride * 4) {
        float4 v = *(const float4*)(src + i);
        bf16x4 o;
        o[0] = (__bf16)v.x; o[1] = (__bf16)v.y; o[2] = (__bf16)v.z; o[3] = (__bf16)v.w;
        *(bf16x4*)(dst + i) = o;
    }
}

// ---------------------------------------------------------------------------
// GEMM: out[m][n] = sum_k A[m][k] * B[n][k]   (A: [M][K] bf16, B: [N][K] bf16)
// 128x128 tile, BK=64, 256 threads (4 waves, 2x2), reg-staged LDS (+8 pad).
// MODE 0: bf16 out scattered to QKV layout [proj][b*16+h][c][d], Q scaled 1/8.
// MODE 1: f32 out row-major [M][N].
// ---------------------------------------------------------------------------
template <int MODE>
__launch_bounds__(256, 2)
__global__ void gemm_bt(const __bf16* __restrict__ A, const __bf16* __restrict__ Bm,
                        void* __restrict__ Out, int M, int N, int K) {
    __shared__ __bf16 As[128][72];
    __shared__ __bf16 Bs[128][72];
    const int tid = threadIdx.x;
    const int w = tid >> 6, lane = tid & 63;
    const int lr = lane & 15, lg = lane >> 4;
    const int m0 = blockIdx.y * 128, n0 = blockIdx.x * 128;
    const int wm0 = (w >> 1) * 64, wn0 = (w & 1) * 64;

    f32x4 acc[4][4] = {};

    // staging: each thread loads 4x 16B from A and B (rows srow+32i, cols scol..scol+7)
    const int srow = tid >> 3;          // 0..31
    const int scol = (tid & 7) * 8;     // 0..56
    const __bf16* Ap = A + (size_t)(m0 + srow) * K + scol;
    const __bf16* Bp = Bm + (size_t)(n0 + srow) * K + scol;

    bf16x8 ar[4], br[4];
#pragma unroll
    for (int i = 0; i < 4; ++i) {
        ar[i] = *(const bf16x8*)(Ap + (size_t)i * 32 * K);
        br[i] = *(const bf16x8*)(Bp + (size_t)i * 32 * K);
    }

    const int nt = K >> 6;
    for (int t = 0; t < nt; ++t) {
        __syncthreads();
#pragma unroll
        for (int i = 0; i < 4; ++i) {
            *(bf16x8*)&As[srow + i * 32][scol] = ar[i];
            *(bf16x8*)&Bs[srow + i * 32][scol] = br[i];
        }
        __syncthreads();
        if (t + 1 < nt) {
            const __bf16* Ap2 = Ap + (size_t)(t + 1) * 64;
            const __bf16* Bp2 = Bp + (size_t)(t + 1) * 64;
#pragma unroll
            for (int i = 0; i < 4; ++i) {
                ar[i] = *(const bf16x8*)(Ap2 + (size_t)i * 32 * K);
                br[i] = *(const bf16x8*)(Bp2 + (size_t)i * 32 * K);
            }
        }
#pragma unroll
        for (int kk = 0; kk < 2; ++kk) {
            bf16x8 af[4], bf[4];
#pragma unroll
            for (int mi = 0; mi < 4; ++mi)
                af[mi] = *(const bf16x8*)&As[wm0 + mi * 16 + lr][kk * 32 + lg * 8];
#pragma unroll
            for (int ni = 0; ni < 4; ++ni)
                bf[ni] = *(const bf16x8*)&Bs[wn0 + ni * 16 + lr][kk * 32 + lg * 8];
#pragma unroll
            for (int mi = 0; mi < 4; ++mi)
#pragma unroll
                for (int ni = 0; ni < 4; ++ni)
                    acc[mi][ni] = __builtin_amdgcn_mfma_f32_16x16x32_bf16(
                        af[mi], bf[ni], acc[mi][ni], 0, 0, 0);
        }
    }

    // epilogue: D layout col = lane&15 (n), row = (lane>>4)*4 + r (m)
#pragma unroll
    for (int mi = 0; mi < 4; ++mi)
#pragma unroll
        for (int ni = 0; ni < 4; ++ni)
#pragma unroll
            for (int r = 0; r < 4; ++r) {
                int m = m0 + wm0 + mi * 16 + lg * 4 + r;
                int n = n0 + wn0 + ni * 16 + lr;
                float v = acc[mi][ni][r];
                if (MODE == 0) {
                    int proj = n >> 10, nn = n & 1023;
                    float scale = (proj == 0) ? 0.125f : 1.0f;  // fold 1/sqrt(64) into Q
                    int h = nn >> 6, d = nn & 63;
                    int b = m >> 11, c = m & 2047;
                    ((__bf16*)Out)[(size_t)proj * 8388608 +
                                   ((size_t)(b * 16 + h) * 2048 + c) * 64 + d] =
                        (__bf16)(v * scale);
                } else {
                    ((float*)Out)[(size_t)m * N + n] = v;
                }
            }
}

// ---------------------------------------------------------------------------
// Flash attention (causal). One block per (b*16+h, q-tile of 64 rows).
// 4 waves x 16 q-rows. Q pre-scaled by 1/8. K,V: [bh][2048][64] bf16.
// Aout: [b][c][h*64+d] bf16.
// ---------------------------------------------------------------------------
__launch_bounds__(256, 4)
__global__ void attn_fwd(const __bf16* __restrict__ Q, const __bf16* __restrict__ K,
                         const __bf16* __restrict__ V, __bf16* __restrict__ Aout) {
    __shared__ __bf16 Plds[4][16][72];
    const int qt = blockIdx.x;   // 0..31
    const int bh = blockIdx.y;   // 0..63
    const int w = threadIdx.x >> 6, lane = threadIdx.x & 63;
    const int lr = lane & 15, lg = lane >> 4;
    const __bf16* Qb = Q + (size_t)bh * 2048 * 64;
    const __bf16* Kb = K + (size_t)bh * 2048 * 64;
    const __bf16* Vb = V + (size_t)bh * 2048 * 64;
    const int q0 = qt * 64 + w * 16;  // wave's first q row

    bf16x8 qf[2];
#pragma unroll
    for (int kk = 0; kk < 2; ++kk)
        qf[kk] = *(const bf16x8*)&Qb[(size_t)(q0 + lr) * 64 + kk * 32 + lg * 8];

    f32x4 o[4] = {};
    float mrow[4], lrow[4];
#pragma unroll
    for (int r = 0; r < 4; ++r) { mrow[r] = NEG_INF; lrow[r] = 0.f; }

    const int nt = qt + 1;  // k-tiles 0..qt (all fully valid except t==qt)
    for (int t = 0; t < nt; ++t) {
        const int k0 = t * 64;
        f32x4 s[4] = {};
#pragma unroll
        for (int sub = 0; sub < 4; ++sub)
#pragma unroll
            for (int kk = 0; kk < 2; ++kk) {
                bf16x8 kf = *(const bf16x8*)&Kb[(size_t)(k0 + sub * 16 + lr) * 64 + kk * 32 + lg * 8];
                s[sub] = __builtin_amdgcn_mfma_f32_16x16x32_bf16(qf[kk], kf, s[sub], 0, 0, 0);
            }
        if (t == qt) {  // diagonal tile: mask k > q
#pragma unroll
            for (int sub = 0; sub < 4; ++sub)
#pragma unroll
                for (int r = 0; r < 4; ++r) {
                    int kcol = k0 + sub * 16 + lr;
                    int mr = q0 + lg * 4 + r;
                    if (kcol > mr) s[sub][r] = NEG_INF;
                }
        }
        // online softmax per row r (row spread over the 16 lanes sharing lg)
#pragma unroll
        for (int r = 0; r < 4; ++r) {
            float v0 = fmaxf(fmaxf(s[0][r], s[1][r]), fmaxf(s[2][r], s[3][r]));
            v0 = fmaxf(v0, __shfl_xor(v0, 1));
            v0 = fmaxf(v0, __shfl_xor(v0, 2));
            v0 = fmaxf(v0, __shfl_xor(v0, 4));
            v0 = fmaxf(v0, __shfl_xor(v0, 8));
            float mnew = fmaxf(mrow[r], v0);
            float alpha = __expf(mrow[r] - mnew);
            float rs = 0.f;
#pragma unroll
            for (int sub = 0; sub < 4; ++sub) {
                float p = __expf(s[sub][r] - mnew);
                s[sub][r] = p;
                rs += p;
            }
            rs += __shfl_xor(rs, 1);
            rs += __shfl_xor(rs, 2);
            rs += __shfl_xor(rs, 4);
            rs += __shfl_xor(rs, 8);
            lrow[r] = lrow[r] * alpha + rs;
            mrow[r] = mnew;
#pragma unroll
            for (int sub = 0; sub < 4; ++sub) o[sub][r] *= alpha;
        }
        // P (f32, D-layout) -> LDS bf16 so it can be re-read as MFMA A-fragments
#pragma unroll
        for (int sub = 0; sub < 4; ++sub)
#pragma unroll
            for (int r = 0; r < 4; ++r)
                Plds[w][lg * 4 + r][sub * 16 + lr] = (__bf16)s[sub][r];
        __syncthreads();
        bf16x8 pa[2];
#pragma unroll
        for (int kk = 0; kk < 2; ++kk)
            pa[kk] = *(const bf16x8*)&Plds[w][lr][kk * 32 + lg * 8];
        // PV: B-fragment = V[k][d] (scalar loads, V tile is L2-resident)
#pragma unroll
        for (int ni = 0; ni < 4; ++ni) {
#pragma unroll
            for (int kk = 0; kk < 2; ++kk) {
                bf16x8 vf;
#pragma unroll
                for (int j = 0; j < 8; ++j)
                    vf[j] = Vb[(size_t)(k0 + kk * 32 + lg * 8 + j) * 64 + ni * 16 + lr];
                o[ni] = __builtin_amdgcn_mfma_f32_16x16x32_bf16(pa[kk], vf, o[ni], 0, 0, 0);
            }
        }
        __syncthreads();
    }
    // epilogue: Aout[b][c][h*64+d] = o / l
    const int b = bh >> 4, h = bh & 15;
#pragma unroll
    for (int ni = 0; ni < 4; ++ni)
#pragma unroll
        for (int r = 0; r < 4; ++r) {
            int c = q0 + lg * 4 + r;
            int d = h * 64 + ni * 16 + lr;
            Aout[((size_t)b * 2048 + c) * 1024 + d] = (__bf16)(o[ni][r] / lrow[r]);
        }
}

// ---------------------------------------------------------------------------
// launch
// ---------------------------------------------------------------------------
extern "C" void kernel_launch(void* const* d_in, const int* in_sizes, int n_in,
                              void* d_out, int out_size, void* d_ws, size_t ws_size,
                              hipStream_t stream) {
    const float* x  = (const float*)d_in[0];
    const float* Wk = (const float*)d_in[1];   // NOTE: dict order x, Wk, Wq, Wv, Wo
    const float* Wq = (const float*)d_in[2];
    const float* Wv = (const float*)d_in[3];
    const float* Wo = (const float*)d_in[4];

    char* ws = (char*)d_ws;
    __bf16* xb   = (__bf16*)(ws);                 // [8192][1024]        16 MB
    __bf16* wqkv = (__bf16*)(ws + 16777216);      // [3072][1024]         6 MB
    __bf16* wo_b = (__bf16*)(ws + 23068672);      // [1024][1024]         2 MB
    __bf16* qkv  = (__bf16*)(ws + 25165824);      // 3 x [64][2048][64]  48 MB
    __bf16* aout = (__bf16*)(ws + 75497472);      // [8192][1024]        16 MB
    float* out = (float*)d_out;

    cvt_f32_bf16<<<2048, 256, 0, stream>>>(x, xb, 8388608);
    cvt_f32_bf16<<<1024, 256, 0, stream>>>(Wq, wqkv, 1048576);            // proj 0 = Q
    cvt_f32_bf16<<<1024, 256, 0, stream>>>(Wk, wqkv + 1048576, 1048576);  // proj 1 = K
    cvt_f32_bf16<<<1024, 256, 0, stream>>>(Wv, wqkv + 2097152, 1048576);  // proj 2 = V
    cvt_f32_bf16<<<1024, 256, 0, stream>>>(Wo, wo_b, 1048576);

    gemm_bt<0><<<dim3(24, 64), 256, 0, stream>>>(xb, wqkv, qkv, 8192, 3072, 1024);
    attn_fwd<<<dim3(32, 64), 256, 0, stream>>>(qkv, qkv + 8388608, qkv + 16777216, aout);
    gemm_bt<1><<<dim3(8, 64), 256, 0, stream>>>(aout, wo_b, out, 8192, 1024, 1024);
}

// Round 2
// 192.126 us; speedup vs baseline: 2.4722x; 2.4722x over previous
//
#include <hip/hip_runtime.h>
#include <hip/hip_bf16.h>

typedef __bf16 bf16x8 __attribute__((ext_vector_type(8)));
typedef __bf16 bf16x4 __attribute__((ext_vector_type(4)));
typedef float f32x4 __attribute__((ext_vector_type(4)));

#define NEG_INF (-__builtin_inff())

// ---------------------------------------------------------------------------
// f32 -> bf16 conversion (vectorized, grid-stride)
// ---------------------------------------------------------------------------
__global__ void cvt_f32_bf16(const float* __restrict__ src, __bf16* __restrict__ dst, int n) {
    int idx = blockIdx.x * blockDim.x + threadIdx.x;
    int stride = gridDim.x * blockDim.x;
    for (int i = idx * 4; i < n; i += stride * 4) {
        float4 v = *(const float4*)(src + i);
        bf16x4 o;
        o[0] = (__bf16)v.x; o[1] = (__bf16)v.y; o[2] = (__bf16)v.z; o[3] = (__bf16)v.w;
        *(bf16x4*)(dst + i) = o;
    }
}

// ---------------------------------------------------------------------------
// GEMM: out[m][n] = sum_k A[m][k] * B[n][k]   (A: [M][K] bf16, B: [N][K] bf16)
// 128x128 tile, BK=64, 256 threads (4 waves, 2x2), reg-staged LDS (+8 pad).
// MODE 0: bf16 out scattered to QKV layout; Q scaled 1/8; V written TRANSPOSED
//         as Vt[bh][d][2048].
// MODE 1: f32 out row-major [M][N].
// ---------------------------------------------------------------------------
template <int MODE>
__launch_bounds__(256, 2)
__global__ void gemm_bt(const __bf16* __restrict__ A, const __bf16* __restrict__ Bm,
                        void* __restrict__ Out, int M, int N, int K) {
    __shared__ __bf16 As[128][72];
    __shared__ __bf16 Bs[128][72];
    const int tid = threadIdx.x;
    const int w = tid >> 6, lane = tid & 63;
    const int lr = lane & 15, lg = lane >> 4;
    const int m0 = blockIdx.y * 128, n0 = blockIdx.x * 128;
    const int wm0 = (w >> 1) * 64, wn0 = (w & 1) * 64;

    f32x4 acc[4][4] = {};

    const int srow = tid >> 3;          // 0..31
    const int scol = (tid & 7) * 8;     // 0..56
    const __bf16* Ap = A + (size_t)(m0 + srow) * K + scol;
    const __bf16* Bp = Bm + (size_t)(n0 + srow) * K + scol;

    bf16x8 ar[4], br[4];
#pragma unroll
    for (int i = 0; i < 4; ++i) {
        ar[i] = *(const bf16x8*)(Ap + (size_t)i * 32 * K);
        br[i] = *(const bf16x8*)(Bp + (size_t)i * 32 * K);
    }

    const int nt = K >> 6;
    for (int t = 0; t < nt; ++t) {
        __syncthreads();
#pragma unroll
        for (int i = 0; i < 4; ++i) {
            *(bf16x8*)&As[srow + i * 32][scol] = ar[i];
            *(bf16x8*)&Bs[srow + i * 32][scol] = br[i];
        }
        __syncthreads();
        if (t + 1 < nt) {
            const __bf16* Ap2 = Ap + (size_t)(t + 1) * 64;
            const __bf16* Bp2 = Bp + (size_t)(t + 1) * 64;
#pragma unroll
            for (int i = 0; i < 4; ++i) {
                ar[i] = *(const bf16x8*)(Ap2 + (size_t)i * 32 * K);
                br[i] = *(const bf16x8*)(Bp2 + (size_t)i * 32 * K);
            }
        }
#pragma unroll
        for (int kk = 0; kk < 2; ++kk) {
            bf16x8 af[4], bf[4];
#pragma unroll
            for (int mi = 0; mi < 4; ++mi)
                af[mi] = *(const bf16x8*)&As[wm0 + mi * 16 + lr][kk * 32 + lg * 8];
#pragma unroll
            for (int ni = 0; ni < 4; ++ni)
                bf[ni] = *(const bf16x8*)&Bs[wn0 + ni * 16 + lr][kk * 32 + lg * 8];
#pragma unroll
            for (int mi = 0; mi < 4; ++mi)
#pragma unroll
                for (int ni = 0; ni < 4; ++ni)
                    acc[mi][ni] = __builtin_amdgcn_mfma_f32_16x16x32_bf16(
                        af[mi], bf[ni], acc[mi][ni], 0, 0, 0);
        }
    }

    // epilogue: D layout col = lane&15 (n), row = (lane>>4)*4 + r (m)
#pragma unroll
    for (int mi = 0; mi < 4; ++mi)
#pragma unroll
        for (int ni = 0; ni < 4; ++ni)
#pragma unroll
            for (int r = 0; r < 4; ++r) {
                int m = m0 + wm0 + mi * 16 + lg * 4 + r;
                int n = n0 + wn0 + ni * 16 + lr;
                float v = acc[mi][ni][r];
                if (MODE == 0) {
                    int proj = n >> 10, nn = n & 1023;
                    int h = nn >> 6, d = nn & 63;
                    int bb = m >> 11, c = m & 2047;
                    if (proj == 2) {
                        // Vt layout: [bh][d][2048]
                        ((__bf16*)Out)[(size_t)2 * 8388608 +
                                       ((size_t)((bb * 16 + h) * 64 + d)) * 2048 + c] = (__bf16)v;
                    } else {
                        float scale = (proj == 0) ? 0.125f : 1.0f;
                        ((__bf16*)Out)[(size_t)proj * 8388608 +
                                       ((size_t)(bb * 16 + h) * 2048 + c) * 64 + d] =
                            (__bf16)(v * scale);
                    }
                } else {
                    ((float*)Out)[(size_t)m * N + n] = v;
                }
            }
}

// ---------------------------------------------------------------------------
// Flash attention (causal), swapped-QK^T structure.
// Grid: 1024 blocks (XCD-swizzled). Block = (bh, q-tile pair {qt, 31-qt}).
// 4 waves x 16 q-rows each. K tile + V^T tile double-buffered in LDS via
// global_load_lds with XOR-swizzled source (linear dest) + swizzled reads.
// ---------------------------------------------------------------------------
__device__ __forceinline__ unsigned swz(unsigned d) {
    return d ^ (((d >> 7) & 7) << 4);   // 128B rows; spread 16B slots across banks
}

__launch_bounds__(256, 4)
__global__ void attn_fwd(const __bf16* __restrict__ Q, const __bf16* __restrict__ K,
                         const __bf16* __restrict__ Vt, __bf16* __restrict__ Aout) {
    // LDS: K dbuf 2x8KB | Vt dbuf 2x8KB | P 4 waves x 2KB  = 40960 B
    __shared__ char smem[40960];
    const int id = blockIdx.x;
    const int vid = (id & 7) * 128 + (id >> 3);   // bijective XCD swizzle (1024%8==0)
    const int bh = vid >> 4, pr = vid & 15;
    const int w = threadIdx.x >> 6, lane = threadIdx.x & 63;
    const int lr = lane & 15, lg = lane >> 4;
    const char* Kb  = (const char*)(K  + (size_t)bh * 2048 * 64);
    const char* Vtb = (const char*)(Vt + (size_t)bh * 64 * 2048);
    const __bf16* Qb = Q + (size_t)bh * 2048 * 64;
    const int b = bh >> 4, h = bh & 15;
    char* Pb = smem + 32768 + w * 2048;

    for (int pass = 0; pass < 2; ++pass) {
        const int qt = pass ? pr : 31 - pr;       // pair work = 33 tiles, uniform
        const int q0 = qt * 64 + w * 16;
        const int nt = qt + 1;

        bf16x8 qf[2];
#pragma unroll
        for (int kk = 0; kk < 2; ++kk)
            qf[kk] = *(const bf16x8*)&Qb[(size_t)(q0 + lr) * 64 + kk * 32 + lg * 8];

        f32x4 o[4] = {};
        float m = NEG_INF, l = 0.f;

        __syncthreads();   // previous pass/compute fully done before restaging buf0
        // prologue: stage tile 0 -> buf 0 (4x global_load_lds per wave)
        {
            char* kd = smem;
            char* vd = smem + 16384;
#pragma unroll
            for (int i = 0; i < 2; ++i) {
                unsigned c = (unsigned)(w * 2 + i);
                unsigned d = c * 1024 + (unsigned)lane * 16;
                unsigned bs = swz(d);
                __builtin_amdgcn_global_load_lds(
                    (const __attribute__((address_space(1))) void*)(Kb + bs),
                    (__attribute__((address_space(3))) void*)(kd + c * 1024), 16, 0, 0);
                unsigned row = bs >> 7, colb = bs & 127;
                __builtin_amdgcn_global_load_lds(
                    (const __attribute__((address_space(1))) void*)(Vtb + (size_t)row * 4096 + colb),
                    (__attribute__((address_space(3))) void*)(vd + c * 1024), 16, 0, 0);
            }
        }

        for (int t = 0; t < nt; ++t) {
            __syncthreads();   // implicit vmcnt(0) drain: tile t resident; all waves synced
            if (t + 1 < nt) {  // prefetch t+1 while computing t
                char* kd = smem + ((t + 1) & 1) * 8192;
                char* vd = smem + 16384 + ((t + 1) & 1) * 8192;
#pragma unroll
                for (int i = 0; i < 2; ++i) {
                    unsigned c = (unsigned)(w * 2 + i);
                    unsigned d = c * 1024 + (unsigned)lane * 16;
                    unsigned bs = swz(d);
                    __builtin_amdgcn_global_load_lds(
                        (const __attribute__((address_space(1))) void*)(Kb + (size_t)(t + 1) * 8192 + bs),
                        (__attribute__((address_space(3))) void*)(kd + c * 1024), 16, 0, 0);
                    unsigned row = bs >> 7, colb = bs & 127;
                    __builtin_amdgcn_global_load_lds(
                        (const __attribute__((address_space(1))) void*)(Vtb + (size_t)row * 4096 +
                                                                       (size_t)(t + 1) * 128 + colb),
                        (__attribute__((address_space(3))) void*)(vd + c * 1024), 16, 0, 0);
                }
            }
            const char* Ks = smem + (t & 1) * 8192;
            const char* Vs = smem + 16384 + (t & 1) * 8192;
            const int k0 = t * 64;

            // S^T = K·Q^T : lane owns full row q = q0+lr; s[sub][r] = S[q][k0+sub*16+lg*4+r]
            f32x4 s[4] = {};
#pragma unroll
            for (int kk = 0; kk < 2; ++kk)
#pragma unroll
                for (int sub = 0; sub < 4; ++sub) {
                    bf16x8 kf = *(const bf16x8*)(Ks + swz((unsigned)((sub * 16 + lr) * 128 + kk * 64 + lg * 16)));
                    s[sub] = __builtin_amdgcn_mfma_f32_16x16x32_bf16(kf, qf[kk], s[sub], 0, 0, 0);
                }
            if (t == qt) {
#pragma unroll
                for (int sub = 0; sub < 4; ++sub)
#pragma unroll
                    for (int r = 0; r < 4; ++r)
                        if (k0 + sub * 16 + lg * 4 + r > q0 + lr) s[sub][r] = NEG_INF;
            }
            // online softmax: 16 local vals + 2 shuffles across lg groups
            float mloc = NEG_INF;
#pragma unroll
            for (int sub = 0; sub < 4; ++sub)
#pragma unroll
                for (int r = 0; r < 4; ++r) mloc = fmaxf(mloc, s[sub][r]);
            mloc = fmaxf(mloc, __shfl_xor(mloc, 16));
            mloc = fmaxf(mloc, __shfl_xor(mloc, 32));
            float mnew = fmaxf(m, mloc);
            float alpha = __expf(m - mnew);
            float rs = 0.f;
#pragma unroll
            for (int sub = 0; sub < 4; ++sub)
#pragma unroll
                for (int r = 0; r < 4; ++r) {
                    float p = __expf(s[sub][r] - mnew);
                    s[sub][r] = p;
                    rs += p;
                }
            rs += __shfl_xor(rs, 16);
            rs += __shfl_xor(rs, 32);
            l = l * alpha + rs;
            m = mnew;
#pragma unroll
            for (int ni = 0; ni < 4; ++ni) o[ni] *= alpha;

            // P -> per-wave LDS (vectorized b64 writes, swizzled)
#pragma unroll
            for (int sub = 0; sub < 4; ++sub) {
                bf16x4 pk;
#pragma unroll
                for (int r = 0; r < 4; ++r) pk[r] = (__bf16)s[sub][r];
                *(bf16x4*)(Pb + swz((unsigned)(lr * 128 + sub * 32 + lg * 8))) = pk;
            }
            bf16x8 pfr[2];
#pragma unroll
            for (int kk = 0; kk < 2; ++kk)
                pfr[kk] = *(const bf16x8*)(Pb + swz((unsigned)(lr * 128 + kk * 64 + lg * 16)));

            // O^T += V^T · P^T : o[ni][r] = O[q=q0+lr][d = ni*16 + lg*4 + r]
#pragma unroll
            for (int kk = 0; kk < 2; ++kk)
#pragma unroll
                for (int ni = 0; ni < 4; ++ni) {
                    bf16x8 vf = *(const bf16x8*)(Vs + swz((unsigned)((ni * 16 + lr) * 128 + kk * 64 + lg * 16)));
                    o[ni] = __builtin_amdgcn_mfma_f32_16x16x32_bf16(vf, pfr[kk], o[ni], 0, 0, 0);
                }
        }

        // epilogue: Aout[b][c=q0+lr][h*64 + ni*16 + lg*4 + r], vectorized 8B stores
        float rinv = 1.0f / l;
#pragma unroll
        for (int ni = 0; ni < 4; ++ni) {
            bf16x4 ov;
#pragma unroll
            for (int r = 0; r < 4; ++r) ov[r] = (__bf16)(o[ni][r] * rinv);
            *(bf16x4*)&Aout[((size_t)b * 2048 + q0 + lr) * 1024 + h * 64 + ni * 16 + lg * 4] = ov;
        }
    }
}

// ---------------------------------------------------------------------------
// launch
// ---------------------------------------------------------------------------
extern "C" void kernel_launch(void* const* d_in, const int* in_sizes, int n_in,
                              void* d_out, int out_size, void* d_ws, size_t ws_size,
                              hipStream_t stream) {
    const float* x  = (const float*)d_in[0];
    const float* Wk = (const float*)d_in[1];   // dict order: x, Wk, Wq, Wv, Wo
    const float* Wq = (const float*)d_in[2];
    const float* Wv = (const float*)d_in[3];
    const float* Wo = (const float*)d_in[4];

    char* ws = (char*)d_ws;
    __bf16* xb   = (__bf16*)(ws);                 // [8192][1024]        16 MB
    __bf16* wqkv = (__bf16*)(ws + 16777216);      // [3072][1024]         6 MB
    __bf16* wo_b = (__bf16*)(ws + 23068672);      // [1024][1024]         2 MB
    __bf16* qkv  = (__bf16*)(ws + 25165824);      // Q,K: [64][2048][64]; Vt: [64][64][2048]
    __bf16* aout = (__bf16*)(ws + 75497472);      // [8192][1024]        16 MB
    float* out = (float*)d_out;

    cvt_f32_bf16<<<2048, 256, 0, stream>>>(x, xb, 8388608);
    cvt_f32_bf16<<<1024, 256, 0, stream>>>(Wq, wqkv, 1048576);            // proj 0 = Q
    cvt_f32_bf16<<<1024, 256, 0, stream>>>(Wk, wqkv + 1048576, 1048576);  // proj 1 = K
    cvt_f32_bf16<<<1024, 256, 0, stream>>>(Wv, wqkv + 2097152, 1048576);  // proj 2 = V
    cvt_f32_bf16<<<1024, 256, 0, stream>>>(Wo, wo_b, 1048576);

    gemm_bt<0><<<dim3(24, 64), 256, 0, stream>>>(xb, wqkv, qkv, 8192, 3072, 1024);
    attn_fwd<<<dim3(1024), 256, 0, stream>>>(qkv, qkv + 8388608, qkv + 16777216, aout);
    gemm_bt<1><<<dim3(8, 64), 256, 0, stream>>>(aout, wo_b, out, 8192, 1024, 1024);
}